// Round 1
// baseline (266.962 us; speedup 1.0000x reference)
//
#include <hip/hip_runtime.h>

#define BB 2
#define NN 2048
#define DD 256
#define HH 8
#define HD 32
#define EPS 1e-5f

__device__ __forceinline__ float leaky(float s){ return s >= 0.f ? s : 0.2f*s; }

// K0: uq[h][d] = sum_t Wq[d][h*HD+t]*a_q[h][t]; cq[h] = sum_t bq[h*HD+t]*a_q[h][t]; same for k.
__global__ void k_prep(const float* __restrict__ Wq, const float* __restrict__ bq,
                       const float* __restrict__ Wk, const float* __restrict__ bk,
                       const float* __restrict__ aa, float* __restrict__ uq,
                       float* __restrict__ uk, float* __restrict__ cq, float* __restrict__ ck){
    int h = blockIdx.x;      // 0..7
    int d = threadIdx.x;     // 0..255
    float accq = 0.f, acck = 0.f;
    #pragma unroll
    for(int t=0; t<HD; t++){
        accq += Wq[(size_t)d*DD + h*HD + t] * aa[h*2*HD + t];
        acck += Wk[(size_t)d*DD + h*HD + t] * aa[h*2*HD + HD + t];
    }
    uq[h*DD + d] = accq;
    uk[h*DD + d] = acck;
    __shared__ float red[64];
    if(d < HD){
        red[d]      = bq[h*HD+d]*aa[h*2*HD+d];
        red[32+d]   = bk[h*HD+d]*aa[h*2*HD+HD+d];
    }
    __syncthreads();
    if(d==0){ float s=0.f; for(int t=0;t<32;t++) s+=red[t];    cq[h]=s; }
    if(d==1){ float s=0.f; for(int t=0;t<32;t++) s+=red[32+t]; ck[h]=s; }
}

// K1: sq[b][i][h] = x_row . uq[h] + cq[h];  skT[b][h][i] = x_row . uk[h] + ck[h]
__global__ void k_sqsk(const float* __restrict__ x, const float* __restrict__ uq,
                       const float* __restrict__ uk, const float* __restrict__ cq,
                       const float* __restrict__ ck, float* __restrict__ sq,
                       float* __restrict__ skT){
    int t = threadIdx.x;
    int w = t >> 6, l = t & 63;
    int R = blockIdx.x*4 + w;           // 0..4095 global row
    const float4 xv = *reinterpret_cast<const float4*>(x + (size_t)R*DD + l*4);
    float vq = 0.f, vk = 0.f;
    #pragma unroll
    for(int h=0; h<HH; h++){
        float4 uqv = *reinterpret_cast<const float4*>(uq + h*DD + l*4);
        float4 ukv = *reinterpret_cast<const float4*>(uk + h*DD + l*4);
        float aq = xv.x*uqv.x + xv.y*uqv.y + xv.z*uqv.z + xv.w*uqv.w;
        float ak = xv.x*ukv.x + xv.y*ukv.y + xv.z*ukv.z + xv.w*ukv.w;
        #pragma unroll
        for(int off=32; off>=1; off>>=1){
            aq += __shfl_xor(aq, off);
            ak += __shfl_xor(ak, off);
        }
        if(l == h){ vq = aq; vk = ak; }
    }
    if(l < HH){
        int b = R >> 11, i = R & (NN-1);
        sq[(size_t)R*HH + l] = vq + cq[l];
        skT[((size_t)b*HH + l)*NN + i] = vk + ck[l];
    }
}

// K1b: Mk[b][h] = max_j skT[b][h][j]
__global__ void k_maxsk(const float* __restrict__ skT, float* __restrict__ Mk){
    int bh = blockIdx.x;   // 0..15
    int t = threadIdx.x;   // 256
    float m = -1e30f;
    for(int j=t; j<NN; j+=256) m = fmaxf(m, skT[(size_t)bh*NN + j]);
    #pragma unroll
    for(int off=32; off>=1; off>>=1) m = fmaxf(m, __shfl_xor(m, off));
    __shared__ float red[4];
    if((t&63)==0) red[t>>6] = m;
    __syncthreads();
    if(t==0) Mk[bh] = fmaxf(fmaxf(red[0],red[1]), fmaxf(red[2],red[3]));
}

// Kv: v = x @ Wv + bv   (16 rows x 256 cols per block)
__global__ __launch_bounds__(256, 2)
void k_vproj(const float* __restrict__ x, const float* __restrict__ Wv,
             const float* __restrict__ bv, float* __restrict__ v){
    __shared__ float xL[16][DD];
    int t = threadIdx.x;
    int r0 = blockIdx.x * 16;
    #pragma unroll
    for(int r=0;r<16;r++) xL[r][t] = x[((size_t)r0+r)*DD + t];
    __syncthreads();
    float acc[16];
    #pragma unroll
    for(int r=0;r<16;r++) acc[r]=0.f;
    for(int k=0;k<DD;k+=4){
        float w0 = Wv[(size_t)k*DD + t];
        float w1 = Wv[(size_t)(k+1)*DD + t];
        float w2 = Wv[(size_t)(k+2)*DD + t];
        float w3 = Wv[(size_t)(k+3)*DD + t];
        #pragma unroll
        for(int r=0;r<16;r++){
            float4 xv = *reinterpret_cast<const float4*>(&xL[r][k]);
            acc[r] += xv.x*w0 + xv.y*w1 + xv.z*w2 + xv.w*w3;
        }
    }
    float bb = bv[t];
    #pragma unroll
    for(int r=0;r<16;r++) v[((size_t)r0+r)*DD + t] = acc[r] + bb;
}

// K2: denominator pass.  M[b,i,h] = leaky(sq + Mk)  (upper bound, leaky monotone)
__global__ void k_denom(const int* __restrict__ adj, const float* __restrict__ sq,
                        const float* __restrict__ skT, const float* __restrict__ Mk,
                        float* __restrict__ Mrow, float* __restrict__ isum){
    int R = blockIdx.x;           // b*N + i
    int b = R >> 11;
    int t = threadIdx.x;
    float Mh[HH], sum[HH], sqh[HH];
    #pragma unroll
    for(int h=0; h<HH; h++){
        sqh[h] = sq[(size_t)R*HH + h];
        Mh[h] = leaky(sqh[h] + Mk[b*HH + h]);
        sum[h] = 0.f;
    }
    const int* arow = adj + (size_t)R*NN;
    for(int j0=0; j0<NN; j0+=256){
        int a = arow[j0+t];
        if(a != 0){
            #pragma unroll
            for(int h=0; h<HH; h++){
                float s = leaky(sqh[h] + skT[((size_t)b*HH+h)*NN + j0 + t]);
                sum[h] += __expf(s - Mh[h]);
            }
        }
    }
    #pragma unroll
    for(int h=0;h<HH;h++){
        #pragma unroll
        for(int off=32; off>=1; off>>=1) sum[h] += __shfl_xor(sum[h], off);
    }
    __shared__ float red[4][HH];
    int w = t>>6, l = t&63;
    if(l==0){
        #pragma unroll
        for(int h=0;h<HH;h++) red[w][h]=sum[h];
    }
    __syncthreads();
    if(t < HH){
        float s = red[0][t]+red[1][t]+red[2][t]+red[3][t];
        Mrow[(size_t)R*HH + t] = leaky(sq[(size_t)R*HH + t] + Mk[b*HH + t]);
        isum[(size_t)R*HH + t] = 1.f/s;
    }
}

// K3: the hot kernel. Per (i-tile of 32, b, j-quarter): recompute w per 32x32 j-tile,
// write mean_w, accumulate attended partial = w @ v.
#define TI 32
#define JT 32
#define JC 4
#define JPC (NN/JC)   // 512

__global__ __launch_bounds__(256, 2)
void k_attn(const int* __restrict__ adj, const float* __restrict__ sq,
            const float* __restrict__ skT, const float* __restrict__ Mrow,
            const float* __restrict__ isum, const float* __restrict__ v,
            float* __restrict__ meanw, float* __restrict__ attp){
    __shared__ float wLDS[HH][TI][JT];     // 32 KB
    __shared__ float vLDS[DD][36];         // 36 KB (padded stride 36)
    __shared__ float skLDS[HH][JT];        // 1 KB
    __shared__ float sqL[TI][HH], ML[TI][HH], isL[TI][HH];  // 3 KB

    int t  = threadIdx.x;
    int it = blockIdx.x;       // 0..63
    int b  = blockIdx.y;       // 0..1
    int jc = blockIdx.z;       // 0..3
    int i0 = it*TI;
    int R0 = b*NN + i0;

    { // per-row params, once
        int i = t >> 3, h = t & 7;
        sqL[i][h] = sq[(size_t)(R0+i)*HH + h];
        ML[i][h]  = Mrow[(size_t)(R0+i)*HH + h];
        isL[i][h] = isum[(size_t)(R0+i)*HH + h];
    }

    float acc[16][2];
    #pragma unroll
    for(int r=0;r<16;r++){ acc[r][0]=0.f; acc[r][1]=0.f; }

    int h  = (t>>4)&7;
    int cp = t&15;
    int ih = t>>7;
    int d0 = h*HD + cp;        // and d0+16

    for(int jt0=0; jt0<JPC; jt0+=JT){
        int jb = jc*JPC + jt0;
        __syncthreads();   // protect vLDS/skLDS from previous iteration's readers
        // stage v transposed: vLDS[d][jj] = v[b][jb+jj][d]
        #pragma unroll
        for(int r4=0; r4<8; r4++){
            float4 vv;
            vv.x = v[((size_t)b*NN + jb + r4*4 + 0)*DD + t];
            vv.y = v[((size_t)b*NN + jb + r4*4 + 1)*DD + t];
            vv.z = v[((size_t)b*NN + jb + r4*4 + 2)*DD + t];
            vv.w = v[((size_t)b*NN + jb + r4*4 + 3)*DD + t];
            *reinterpret_cast<float4*>(&vLDS[t][r4*4]) = vv;
        }
        { int hh = t>>5, jj = t&31; skLDS[hh][jj] = skT[((size_t)b*HH+hh)*NN + jb + jj]; }
        __syncthreads();

        // Phase A: w tile + mean_w
        #pragma unroll
        for(int rep=0; rep<4; rep++){
            int p = rep*256 + t;
            int i = p >> 5;        // 0..31
            int jj = p & 31;
            int a = adj[((size_t)b*NN + i0+i)*NN + jb + jj];
            float wsum = 0.f;
            #pragma unroll
            for(int hh=0; hh<HH; hh++){
                float wv = 0.f;
                if(a){
                    float s = leaky(sqL[i][hh] + skLDS[hh][jj]);
                    wv = __expf(s - ML[i][hh]) * isL[i][hh];
                }
                wLDS[hh][i][jj] = wv;
                wsum += wv;
            }
            meanw[((size_t)b*NN + i0+i)*NN + jb + jj] = wsum * 0.125f;
        }
        __syncthreads();

        // Phase B: acc[i][c] += sum_j w[h][i][j]*v[j][d]
        #pragma unroll
        for(int j4=0; j4<8; j4++){
            float4 va = *reinterpret_cast<const float4*>(&vLDS[d0][j4*4]);
            float4 vb = *reinterpret_cast<const float4*>(&vLDS[d0+16][j4*4]);
            #pragma unroll
            for(int r=0; r<16; r++){
                int i = ih*16 + r;
                float4 wv = *reinterpret_cast<const float4*>(&wLDS[h][i][j4*4]);
                acc[r][0] += wv.x*va.x + wv.y*va.y + wv.z*va.z + wv.w*va.w;
                acc[r][1] += wv.x*vb.x + wv.y*vb.y + wv.z*vb.z + wv.w*vb.w;
            }
        }
    }
    #pragma unroll
    for(int r=0;r<16;r++){
        int i = ih*16 + r;
        attp[(((size_t)jc*BB + b)*NN + i0+i)*DD + d0]      = acc[r][0];
        attp[(((size_t)jc*BB + b)*NN + i0+i)*DD + d0+16]   = acc[r][1];
    }
}

// K4: out = LN(attended @ Wo + bo + x)
__global__ __launch_bounds__(256, 2)
void k_out(const float* __restrict__ attp, const float* __restrict__ x,
           const float* __restrict__ Wo, const float* __restrict__ bo,
           const float* __restrict__ g, const float* __restrict__ bln,
           float* __restrict__ out){
    __shared__ float aL[16][DD];
    __shared__ float ps[16][16][2];
    __shared__ float muL[16], rsL[16];
    int t = threadIdx.x;
    int r0 = blockIdx.x*16;
    const size_t PS = (size_t)BB*NN*DD;
    #pragma unroll
    for(int r=0;r<16;r++){
        size_t R = (size_t)r0+r;
        aL[r][t] = attp[0*PS + R*DD + t] + attp[1*PS + R*DD + t]
                 + attp[2*PS + R*DD + t] + attp[3*PS + R*DD + t];
    }
    __syncthreads();
    float acc[16];
    #pragma unroll
    for(int r=0;r<16;r++) acc[r]=0.f;
    for(int k=0;k<DD;k+=4){
        float w0 = Wo[(size_t)k*DD + t];
        float w1 = Wo[(size_t)(k+1)*DD + t];
        float w2 = Wo[(size_t)(k+2)*DD + t];
        float w3 = Wo[(size_t)(k+3)*DD + t];
        #pragma unroll
        for(int r=0;r<16;r++){
            float4 av = *reinterpret_cast<const float4*>(&aL[r][k]);
            acc[r] += av.x*w0 + av.y*w1 + av.z*w2 + av.w*w3;
        }
    }
    float bb = bo[t];
    #pragma unroll
    for(int r=0;r<16;r++) acc[r] += bb + x[((size_t)r0+r)*DD + t];
    __syncthreads();
    #pragma unroll
    for(int r=0;r<16;r++) aL[r][t] = acc[r];
    __syncthreads();
    {
        int rr = t>>4, seg = t&15;
        float s=0.f, sq=0.f;
        #pragma unroll
        for(int e=0;e<16;e++){
            float y = aL[rr][seg*16+e];
            s += y; sq += y*y;
        }
        ps[rr][seg][0]=s; ps[rr][seg][1]=sq;
    }
    __syncthreads();
    if(t<16){
        float s=0.f, sq=0.f;
        #pragma unroll
        for(int e=0;e<16;e++){ s+=ps[t][e][0]; sq+=ps[t][e][1]; }
        float mu = s/256.f;
        float var = sq/256.f - mu*mu;
        muL[t]=mu; rsL[t]=rsqrtf(var+EPS);
    }
    __syncthreads();
    float gg = g[t], bl = bln[t];
    #pragma unroll
    for(int r=0;r<16;r++){
        out[((size_t)r0+r)*DD + t] = (acc[r]-muL[r])*rsL[r]*gg + bl;
    }
}

extern "C" void kernel_launch(void* const* d_in, const int* in_sizes, int n_in,
                              void* d_out, int out_size, void* d_ws, size_t ws_size,
                              hipStream_t stream) {
    const float* x    = (const float*)d_in[0];
    const int*   adj  = (const int*)d_in[1];
    const float* Wq   = (const float*)d_in[2];
    const float* bq   = (const float*)d_in[3];
    const float* Wk   = (const float*)d_in[4];
    const float* bk   = (const float*)d_in[5];
    const float* Wv   = (const float*)d_in[6];
    const float* bv   = (const float*)d_in[7];
    const float* aa   = (const float*)d_in[8];
    const float* Wo   = (const float*)d_in[9];
    const float* bo   = (const float*)d_in[10];
    const float* lng  = (const float*)d_in[11];
    const float* lnb  = (const float*)d_in[12];

    float* out0  = (float*)d_out;                  // (B,N,D)
    float* meanw = out0 + (size_t)BB*NN*DD;        // (B,N,N)

    float* ws   = (float*)d_ws;
    float* uq   = ws;                  // 2048
    float* uk   = uq + 2048;           // 2048
    float* cq   = uk + 2048;           // 16
    float* ck   = cq + 16;             // 16
    float* Mk   = ck + 16;             // 16
    float* sqv  = Mk + 16;             // 32768
    float* skT  = sqv + 32768;         // 32768
    float* Mrow = skT + 32768;         // 32768
    float* isum = Mrow + 32768;        // 32768
    float* v    = isum + 32768;        // 1048576
    float* attp = v + 1048576;         // 4*1048576

    k_prep<<<HH, 256, 0, stream>>>(Wq, bq, Wk, bk, aa, uq, uk, cq, ck);
    k_sqsk<<<(BB*NN)/4, 256, 0, stream>>>(x, uq, uk, cq, ck, sqv, skT);
    k_maxsk<<<BB*HH, 256, 0, stream>>>(skT, Mk);
    k_vproj<<<(BB*NN)/16, 256, 0, stream>>>(x, Wv, bv, v);
    k_denom<<<BB*NN, 256, 0, stream>>>(adj, sqv, skT, Mk, Mrow, isum);
    k_attn<<<dim3(NN/TI, BB, JC), 256, 0, stream>>>(adj, sqv, skT, Mrow, isum, v, meanw, attp);
    k_out<<<(BB*NN)/16, 256, 0, stream>>>(attp, x, Wo, bo, lng, lnb, out0);
}

// Round 3
// 182.566 us; speedup vs baseline: 1.4623x; 1.4623x over previous
//
#include <hip/hip_runtime.h>

#define BB 2
#define NN 2048
#define DD 256
#define HH 8
#define HD 32
#define EPS 1e-5f

typedef __attribute__((ext_vector_type(8))) short bf16x8;
typedef __attribute__((ext_vector_type(4))) float f32x4;

__device__ __forceinline__ float leaky(float s){ return s >= 0.f ? s : 0.2f*s; }

__device__ __forceinline__ ushort f2bf(float f){
    union{ float f; unsigned u; } c; c.f = f;
    unsigned r = c.u + 0x7fffu + ((c.u >> 16) & 1u);
    return (ushort)(r >> 16);
}

// K0: uq[h][d] = sum_t Wq[d][h*HD+t]*a_q[h][t]; cq[h] = sum_t bq[h*HD+t]*a_q[h][t]; same for k.
__global__ void k_prep(const float* __restrict__ Wq, const float* __restrict__ bq,
                       const float* __restrict__ Wk, const float* __restrict__ bk,
                       const float* __restrict__ aa, float* __restrict__ uq,
                       float* __restrict__ uk, float* __restrict__ cq, float* __restrict__ ck){
    int h = blockIdx.x;      // 0..7
    int d = threadIdx.x;     // 0..255
    float accq = 0.f, acck = 0.f;
    #pragma unroll
    for(int t=0; t<HD; t++){
        accq += Wq[(size_t)d*DD + h*HD + t] * aa[h*2*HD + t];
        acck += Wk[(size_t)d*DD + h*HD + t] * aa[h*2*HD + HD + t];
    }
    uq[h*DD + d] = accq;
    uk[h*DD + d] = acck;
    __shared__ float red[64];
    if(d < HD){
        red[d]      = bq[h*HD+d]*aa[h*2*HD+d];
        red[32+d]   = bk[h*HD+d]*aa[h*2*HD+HD+d];
    }
    __syncthreads();
    if(d==0){ float s=0.f; for(int t=0;t<32;t++) s+=red[t];    cq[h]=s; }
    if(d==1){ float s=0.f; for(int t=0;t<32;t++) s+=red[32+t]; ck[h]=s; }
}

// K1: sq[b][i][h] = x_row . uq[h] + cq[h];  skT[b][h][i] = x_row . uk[h] + ck[h]
__global__ void k_sqsk(const float* __restrict__ x, const float* __restrict__ uq,
                       const float* __restrict__ uk, const float* __restrict__ cq,
                       const float* __restrict__ ck, float* __restrict__ sq,
                       float* __restrict__ skT){
    int t = threadIdx.x;
    int w = t >> 6, l = t & 63;
    int R = blockIdx.x*4 + w;           // 0..4095 global row
    const float4 xv = *reinterpret_cast<const float4*>(x + (size_t)R*DD + l*4);
    float vq = 0.f, vk = 0.f;
    #pragma unroll
    for(int h=0; h<HH; h++){
        float4 uqv = *reinterpret_cast<const float4*>(uq + h*DD + l*4);
        float4 ukv = *reinterpret_cast<const float4*>(uk + h*DD + l*4);
        float aq = xv.x*uqv.x + xv.y*uqv.y + xv.z*uqv.z + xv.w*uqv.w;
        float ak = xv.x*ukv.x + xv.y*ukv.y + xv.z*ukv.z + xv.w*ukv.w;
        #pragma unroll
        for(int off=32; off>=1; off>>=1){
            aq += __shfl_xor(aq, off);
            ak += __shfl_xor(ak, off);
        }
        if(l == h){ vq = aq; vk = ak; }
    }
    if(l < HH){
        int b = R >> 11, i = R & (NN-1);
        sq[(size_t)R*HH + l] = vq + cq[l];
        skT[((size_t)b*HH + l)*NN + i] = vk + ck[l];
    }
}

// K1b: Mk[b][h] = max_j skT[b][h][j]
__global__ void k_maxsk(const float* __restrict__ skT, float* __restrict__ Mk){
    int bh = blockIdx.x;   // 0..15
    int t = threadIdx.x;   // 256
    float m = -1e30f;
    for(int j=t; j<NN; j+=256) m = fmaxf(m, skT[(size_t)bh*NN + j]);
    #pragma unroll
    for(int off=32; off>=1; off>>=1) m = fmaxf(m, __shfl_xor(m, off));
    __shared__ float red[4];
    if((t&63)==0) red[t>>6] = m;
    __syncthreads();
    if(t==0) Mk[bh] = fmaxf(fmaxf(red[0],red[1]), fmaxf(red[2],red[3]));
}

// Kv: v = x @ Wv + bv   (16 rows x 256 cols per block)
__global__ __launch_bounds__(256, 2)
void k_vproj(const float* __restrict__ x, const float* __restrict__ Wv,
             const float* __restrict__ bv, float* __restrict__ v){
    __shared__ float xL[16][DD];
    int t = threadIdx.x;
    int r0 = blockIdx.x * 16;
    #pragma unroll
    for(int r=0;r<16;r++) xL[r][t] = x[((size_t)r0+r)*DD + t];
    __syncthreads();
    float acc[16];
    #pragma unroll
    for(int r=0;r<16;r++) acc[r]=0.f;
    for(int k=0;k<DD;k+=4){
        float w0 = Wv[(size_t)k*DD + t];
        float w1 = Wv[(size_t)(k+1)*DD + t];
        float w2 = Wv[(size_t)(k+2)*DD + t];
        float w3 = Wv[(size_t)(k+3)*DD + t];
        #pragma unroll
        for(int r=0;r<16;r++){
            float4 xv = *reinterpret_cast<const float4*>(&xL[r][k]);
            acc[r] += xv.x*w0 + xv.y*w1 + xv.z*w2 + xv.w*w3;
        }
    }
    float bb = bv[t];
    #pragma unroll
    for(int r=0;r<16;r++) v[((size_t)r0+r)*DD + t] = acc[r] + bb;
}

// K2: denominator pass.  M[b,i,h] = leaky(sq + Mk)  (upper bound, leaky monotone)
__global__ void k_denom(const int* __restrict__ adj, const float* __restrict__ sq,
                        const float* __restrict__ skT, const float* __restrict__ Mk,
                        float* __restrict__ Mrow, float* __restrict__ isum){
    int R = blockIdx.x;           // b*N + i
    int b = R >> 11;
    int t = threadIdx.x;
    float Mh[HH], sum[HH], sqh[HH];
    #pragma unroll
    for(int h=0; h<HH; h++){
        sqh[h] = sq[(size_t)R*HH + h];
        Mh[h] = leaky(sqh[h] + Mk[b*HH + h]);
        sum[h] = 0.f;
    }
    const int* arow = adj + (size_t)R*NN;
    for(int j0=0; j0<NN; j0+=256){
        int a = arow[j0+t];
        if(a != 0){
            #pragma unroll
            for(int h=0; h<HH; h++){
                float s = leaky(sqh[h] + skT[((size_t)b*HH+h)*NN + j0 + t]);
                sum[h] += __expf(s - Mh[h]);
            }
        }
    }
    #pragma unroll
    for(int h=0;h<HH;h++){
        #pragma unroll
        for(int off=32; off>=1; off>>=1) sum[h] += __shfl_xor(sum[h], off);
    }
    __shared__ float red[4][HH];
    int w = t>>6, l = t&63;
    if(l==0){
        #pragma unroll
        for(int h=0;h<HH;h++) red[w][h]=sum[h];
    }
    __syncthreads();
    if(t < HH){
        float s = red[0][t]+red[1][t]+red[2][t]+red[3][t];
        Mrow[(size_t)R*HH + t] = leaky(sq[(size_t)R*HH + t] + Mk[b*HH + t]);
        isum[(size_t)R*HH + t] = 1.f/s;
    }
}

// K3: hot kernel, MFMA version. Per (i-tile 32, b, j-quarter): per 32-j tile,
// compute w (f32 -> meanw exact, bf16 -> LDS), stage v^T bf16, then
// mfma_f32_16x16x32_bf16 accumulate attended partial.
#define TI 32
#define JT 32
#define JC 4
#define JPC (NN/JC)   // 512
#define WPAD 40       // ushort stride (80B, 16B-aligned)

__global__ __launch_bounds__(256, 3)
void k_attn(const int* __restrict__ adj, const float* __restrict__ sq,
            const float* __restrict__ skT, const float* __restrict__ Mrow,
            const float* __restrict__ isum, const float* __restrict__ v,
            float* __restrict__ meanw, float* __restrict__ attp){
    __shared__ ushort wLDS[HH][TI][WPAD];   // 20.0 KB  w[h][i][j] bf16
    __shared__ ushort vLDS[DD][WPAD];       // 20.0 KB  v^T[d][j]  bf16
    __shared__ float  skL[HH][JT];          // 1 KB
    __shared__ float  sqL[TI][HH], ML[TI][HH], isL[TI][HH];  // 3 KB

    int t  = threadIdx.x;
    int it = blockIdx.x;       // 0..63
    int b  = blockIdx.y;       // 0..1
    int jc = blockIdx.z;       // 0..3
    int i0 = it*TI;
    int R0 = b*NN + i0;

    { // per-row params, once
        int i = t >> 3, h = t & 7;
        sqL[i][h] = sq[(size_t)(R0+i)*HH + h];
        ML[i][h]  = Mrow[(size_t)(R0+i)*HH + h];
        isL[i][h] = isum[(size_t)(R0+i)*HH + h];
    }

    int wid = t >> 6;          // wave 0..3 -> heads 2w, 2w+1
    int l   = t & 63;
    int lr  = l & 15;
    int kg  = l >> 4;          // 0..3

    f32x4 acc[2][2][2];        // [head-in-wave][mi][ni]
    #pragma unroll
    for(int hh=0;hh<2;hh++)
        #pragma unroll
        for(int mi=0;mi<2;mi++)
            #pragma unroll
            for(int ni=0;ni<2;ni++) acc[hh][mi][ni] = (f32x4){0.f,0.f,0.f,0.f};

    for(int jt0=0; jt0<JPC; jt0+=JT){
        int jb = jc*JPC + jt0;
        __syncthreads();   // previous tile's MFMA reads done

        // stage v^T bf16: vLDS[d=t][jj] = v[b][jb+jj][t]
        {
            const float* vb = v + ((size_t)b*NN + jb)*DD;
            #pragma unroll
            for(int r4=0; r4<8; r4++){
                float f0 = vb[(size_t)(r4*4+0)*DD + t];
                float f1 = vb[(size_t)(r4*4+1)*DD + t];
                float f2 = vb[(size_t)(r4*4+2)*DD + t];
                float f3 = vb[(size_t)(r4*4+3)*DD + t];
                ushort4 u; u.x=f2bf(f0); u.y=f2bf(f1); u.z=f2bf(f2); u.w=f2bf(f3);
                *reinterpret_cast<ushort4*>(&vLDS[t][r4*4]) = u;
            }
        }
        { int hh = t>>5, jj = t&31; skL[hh][jj] = skT[((size_t)b*HH+hh)*NN + jb + jj]; }
        __syncthreads();   // skL/vLDS staged before Phase A reads skL

        // Phase A: w tile (f32 for meanw, bf16 into wLDS)
        #pragma unroll
        for(int r2=0; r2<2; r2++){
            int idx = r2*256 + t;      // 0..511
            int i  = idx >> 4;         // 0..31
            int jp = idx & 15;
            int jj = jp*2;
            const int2 a2 = *reinterpret_cast<const int2*>(&adj[((size_t)b*NN + i0+i)*NN + jb + jj]);
            float ws0 = 0.f, ws1 = 0.f;
            #pragma unroll
            for(int h=0; h<HH; h++){
                float w0 = 0.f, w1 = 0.f;
                if(a2.x){ float s = leaky(sqL[i][h] + skL[h][jj]);   w0 = __expf(s - ML[i][h]) * isL[i][h]; }
                if(a2.y){ float s = leaky(sqL[i][h] + skL[h][jj+1]); w1 = __expf(s - ML[i][h]) * isL[i][h]; }
                ws0 += w0; ws1 += w1;
                ushort2 u; u.x = f2bf(w0); u.y = f2bf(w1);
                *reinterpret_cast<ushort2*>(&wLDS[h][i][jj]) = u;
            }
            float2 mw; mw.x = ws0*0.125f; mw.y = ws1*0.125f;
            *reinterpret_cast<float2*>(&meanw[((size_t)b*NN + i0+i)*NN + jb + jj]) = mw;
        }
        __syncthreads();

        // Phase B: MFMA. wave wid handles heads 2*wid, 2*wid+1.
        #pragma unroll
        for(int hh=0; hh<2; hh++){
            int h = wid*2 + hh;
            bf16x8 a0 = *reinterpret_cast<const bf16x8*>(&wLDS[h][lr][kg*8]);
            bf16x8 a1 = *reinterpret_cast<const bf16x8*>(&wLDS[h][16+lr][kg*8]);
            bf16x8 b0 = *reinterpret_cast<const bf16x8*>(&vLDS[h*HD + lr][kg*8]);
            bf16x8 b1 = *reinterpret_cast<const bf16x8*>(&vLDS[h*HD + 16 + lr][kg*8]);
            acc[hh][0][0] = __builtin_amdgcn_mfma_f32_16x16x32_bf16(a0, b0, acc[hh][0][0], 0,0,0);
            acc[hh][0][1] = __builtin_amdgcn_mfma_f32_16x16x32_bf16(a0, b1, acc[hh][0][1], 0,0,0);
            acc[hh][1][0] = __builtin_amdgcn_mfma_f32_16x16x32_bf16(a1, b0, acc[hh][1][0], 0,0,0);
            acc[hh][1][1] = __builtin_amdgcn_mfma_f32_16x16x32_bf16(a1, b1, acc[hh][1][1], 0,0,0);
        }
    }

    // Epilogue: C/D layout col=lane&15, row=(lane>>4)*4+reg (m89-verified)
    #pragma unroll
    for(int hh=0;hh<2;hh++)
        #pragma unroll
        for(int mi=0;mi<2;mi++)
            #pragma unroll
            for(int ni=0;ni<2;ni++)
                #pragma unroll
                for(int rg=0; rg<4; rg++){
                    int i = mi*16 + kg*4 + rg;
                    int d = (wid*2+hh)*HD + ni*16 + lr;
                    attp[(((size_t)jc*BB + b)*NN + i0 + i)*DD + d] = acc[hh][mi][ni][rg];
                }
}

// K4: out = LN(attended @ Wo + bo + x)
__global__ __launch_bounds__(256, 2)
void k_out(const float* __restrict__ attp, const float* __restrict__ x,
           const float* __restrict__ Wo, const float* __restrict__ bo,
           const float* __restrict__ g, const float* __restrict__ bln,
           float* __restrict__ out){
    __shared__ float aL[16][DD];
    __shared__ float ps[16][16][2];
    __shared__ float muL[16], rsL[16];
    int t = threadIdx.x;
    int r0 = blockIdx.x*16;
    const size_t PS = (size_t)BB*NN*DD;
    #pragma unroll
    for(int r=0;r<16;r++){
        size_t R = (size_t)r0+r;
        aL[r][t] = attp[0*PS + R*DD + t] + attp[1*PS + R*DD + t]
                 + attp[2*PS + R*DD + t] + attp[3*PS + R*DD + t];
    }
    __syncthreads();
    float acc[16];
    #pragma unroll
    for(int r=0;r<16;r++) acc[r]=0.f;
    for(int k=0;k<DD;k+=4){
        float w0 = Wo[(size_t)k*DD + t];
        float w1 = Wo[(size_t)(k+1)*DD + t];
        float w2 = Wo[(size_t)(k+2)*DD + t];
        float w3 = Wo[(size_t)(k+3)*DD + t];
        #pragma unroll
        for(int r=0;r<16;r++){
            float4 av = *reinterpret_cast<const float4*>(&aL[r][k]);
            acc[r] += av.x*w0 + av.y*w1 + av.z*w2 + av.w*w3;
        }
    }
    float bb = bo[t];
    #pragma unroll
    for(int r=0;r<16;r++) acc[r] += bb + x[((size_t)r0+r)*DD + t];
    __syncthreads();
    #pragma unroll
    for(int r=0;r<16;r++) aL[r][t] = acc[r];
    __syncthreads();
    {
        int rr = t>>4, seg = t&15;
        float s=0.f, sq=0.f;
        #pragma unroll
        for(int e=0;e<16;e++){
            float y = aL[rr][seg*16+e];
            s += y; sq += y*y;
        }
        ps[rr][seg][0]=s; ps[rr][seg][1]=sq;
    }
    __syncthreads();
    if(t<16){
        float s=0.f, sq=0.f;
        #pragma unroll
        for(int e=0;e<16;e++){ s+=ps[t][e][0]; sq+=ps[t][e][1]; }
        float mu = s/256.f;
        float var = sq/256.f - mu*mu;
        muL[t]=mu; rsL[t]=rsqrtf(var+EPS);
    }
    __syncthreads();
    float gg = g[t], bl = bln[t];
    #pragma unroll
    for(int r=0;r<16;r++){
        out[((size_t)r0+r)*DD + t] = (acc[r]-muL[r])*rsL[r]*gg + bl;
    }
}

extern "C" void kernel_launch(void* const* d_in, const int* in_sizes, int n_in,
                              void* d_out, int out_size, void* d_ws, size_t ws_size,
                              hipStream_t stream) {
    const float* x    = (const float*)d_in[0];
    const int*   adj  = (const int*)d_in[1];
    const float* Wq   = (const float*)d_in[2];
    const float* bq   = (const float*)d_in[3];
    const float* Wk   = (const float*)d_in[4];
    const float* bk   = (const float*)d_in[5];
    const float* Wv   = (const float*)d_in[6];
    const float* bv   = (const float*)d_in[7];
    const float* aa   = (const float*)d_in[8];
    const float* Wo   = (const float*)d_in[9];
    const float* bo   = (const float*)d_in[10];
    const float* lng  = (const float*)d_in[11];
    const float* lnb  = (const float*)d_in[12];

    float* out0  = (float*)d_out;                  // (B,N,D)
    float* meanw = out0 + (size_t)BB*NN*DD;        // (B,N,N)

    float* ws   = (float*)d_ws;
    float* uq   = ws;                  // 2048
    float* uk   = uq + 2048;           // 2048
    float* cq   = uk + 2048;           // 16
    float* ck   = cq + 16;             // 16
    float* Mk   = ck + 16;             // 16
    float* sqv  = Mk + 16;             // 32768
    float* skT  = sqv + 32768;         // 32768
    float* Mrow = skT + 32768;         // 32768
    float* isum = Mrow + 32768;        // 32768
    float* v    = isum + 32768;        // 1048576
    float* attp = v + 1048576;         // 4*1048576

    k_prep<<<HH, 256, 0, stream>>>(Wq, bq, Wk, bk, aa, uq, uk, cq, ck);
    k_sqsk<<<(BB*NN)/4, 256, 0, stream>>>(x, uq, uk, cq, ck, sqv, skT);
    k_maxsk<<<BB*HH, 256, 0, stream>>>(skT, Mk);
    k_vproj<<<(BB*NN)/16, 256, 0, stream>>>(x, Wv, bv, v);
    k_denom<<<BB*NN, 256, 0, stream>>>(adj, sqv, skT, Mk, Mrow, isum);
    k_attn<<<dim3(NN/TI, BB, JC), 256, 0, stream>>>(adj, sqv, skT, Mrow, isum, v, meanw, attp);
    k_out<<<(BB*NN)/16, 256, 0, stream>>>(attp, x, Wo, bo, lng, lnb, out0);
}

// Round 4
// 144.491 us; speedup vs baseline: 1.8476x; 1.2635x over previous
//
#include <hip/hip_runtime.h>

#define BB 2
#define NN 2048
#define DD 256
#define HH 8
#define HD 32
#define EPS 1e-5f

typedef __attribute__((ext_vector_type(8))) short bf16x8;
typedef __attribute__((ext_vector_type(4))) float f32x4;
typedef __attribute__((ext_vector_type(8))) unsigned short u16x8;

__device__ __forceinline__ float leaky(float s){ return s >= 0.f ? s : 0.2f*s; }

__device__ __forceinline__ ushort f2bf(float f){
    union{ float f; unsigned u; } c; c.f = f;
    unsigned r = c.u + 0x7fffu + ((c.u >> 16) & 1u);
    return (ushort)(r >> 16);
}
__device__ __forceinline__ float bf2f(ushort u){
    union{ unsigned u; float f; } c; c.u = ((unsigned)u) << 16; return c.f;
}

// K0: uq[h][d], uk[h][d], cq[h], ck[h]
__global__ void k_prep(const float* __restrict__ Wq, const float* __restrict__ bq,
                       const float* __restrict__ Wk, const float* __restrict__ bk,
                       const float* __restrict__ aa, float* __restrict__ uq,
                       float* __restrict__ uk, float* __restrict__ cq, float* __restrict__ ck){
    int h = blockIdx.x;      // 0..7
    int d = threadIdx.x;     // 0..255
    float accq = 0.f, acck = 0.f;
    #pragma unroll
    for(int t=0; t<HD; t++){
        accq += Wq[(size_t)d*DD + h*HD + t] * aa[h*2*HD + t];
        acck += Wk[(size_t)d*DD + h*HD + t] * aa[h*2*HD + HD + t];
    }
    uq[h*DD + d] = accq;
    uk[h*DD + d] = acck;
    __shared__ float red[64];
    if(d < HD){
        red[d]      = bq[h*HD+d]*aa[h*2*HD+d];
        red[32+d]   = bk[h*HD+d]*aa[h*2*HD+HD+d];
    }
    __syncthreads();
    if(d==0){ float s=0.f; for(int t=0;t<32;t++) s+=red[t];    cq[h]=s; }
    if(d==1){ float s=0.f; for(int t=0;t<32;t++) s+=red[32+t]; ck[h]=s; }
}

// K1 fused: per block of 8 rows: v^T bf16 projection + sq/skT scores.
__global__ __launch_bounds__(256, 2)
void k_sqskv(const float* __restrict__ x, const float* __restrict__ Wv,
             const float* __restrict__ bv, const float* __restrict__ uq,
             const float* __restrict__ uk, const float* __restrict__ cq,
             const float* __restrict__ ck, ushort* __restrict__ vT,
             float* __restrict__ sq, float* __restrict__ skT){
    __shared__ float uqL[HH*DD];    // 8KB
    __shared__ float ukL[HH*DD];    // 8KB
    __shared__ float xL[8][DD];     // 8KB
    int t = threadIdx.x;
    int r0 = blockIdx.x * 8;        // global row
    int b  = r0 >> 11;
    int j0 = r0 & (NN-1);
    #pragma unroll
    for(int i=0;i<8;i++){
        uqL[i*DD + t] = uq[i*DD + t];
        ukL[i*DD + t] = uk[i*DD + t];
        xL[i][t] = x[((size_t)r0+i)*DD + t];
    }
    __syncthreads();

    // vproj: thread = col t, 8 rows
    float acc[8];
    #pragma unroll
    for(int r=0;r<8;r++) acc[r]=0.f;
    for(int k=0;k<DD;k+=4){
        float w0 = Wv[(size_t)k*DD + t];
        float w1 = Wv[(size_t)(k+1)*DD + t];
        float w2 = Wv[(size_t)(k+2)*DD + t];
        float w3 = Wv[(size_t)(k+3)*DD + t];
        #pragma unroll
        for(int r=0;r<8;r++){
            float4 xv = *reinterpret_cast<const float4*>(&xL[r][k]);
            acc[r] += xv.x*w0 + xv.y*w1 + xv.z*w2 + xv.w*w3;
        }
    }
    {
        float bb = bv[t];
        u16x8 pack;
        #pragma unroll
        for(int r=0;r<8;r++) pack[r] = f2bf(acc[r] + bb);
        *reinterpret_cast<u16x8*>(&vT[((size_t)b*DD + t)*NN + j0]) = pack;  // vT[b][d][j]
    }

    // sqsk: wave wid -> rows 2*wid, 2*wid+1
    int wid = t >> 6, l = t & 63;
    #pragma unroll
    for(int rr=0; rr<2; rr++){
        int row = wid*2 + rr;
        int R = r0 + row;
        float4 xv = *reinterpret_cast<const float4*>(&xL[row][l*4]);
        float vq = 0.f, vk = 0.f;
        #pragma unroll
        for(int h=0; h<HH; h++){
            float4 uqv = *reinterpret_cast<const float4*>(&uqL[h*DD + l*4]);
            float4 ukv = *reinterpret_cast<const float4*>(&ukL[h*DD + l*4]);
            float aq = xv.x*uqv.x + xv.y*uqv.y + xv.z*uqv.z + xv.w*uqv.w;
            float ak = xv.x*ukv.x + xv.y*ukv.y + xv.z*ukv.z + xv.w*ukv.w;
            #pragma unroll
            for(int off=32; off>=1; off>>=1){
                aq += __shfl_xor(aq, off);
                ak += __shfl_xor(ak, off);
            }
            if(l == h){ vq = aq; vk = ak; }
        }
        if(l < HH){
            sq[(size_t)R*HH + l] = vq + cq[l];
            skT[((size_t)b*HH + l)*NN + (R & (NN-1))] = vk + ck[l];
        }
    }
}

// K2: per row: unmasked per-head max over skT (pass1) then masked exp-sum (pass2).
// Output Madj = leaky(sq+max) + ln(sum)  ->  w = exp(s - Madj), normalized.
__global__ void k_denom(const int* __restrict__ adj, const float* __restrict__ sq,
                        const float* __restrict__ skT, float* __restrict__ Madj){
    int R = blockIdx.x;           // b*N + i
    int b = R >> 11;
    int t = threadIdx.x;
    float sqh[HH], mx[HH], sum[HH];
    #pragma unroll
    for(int h=0; h<HH; h++){ sqh[h] = sq[(size_t)R*HH + h]; mx[h] = -1e30f; }

    for(int j0=0; j0<NN; j0+=256){
        #pragma unroll
        for(int h=0; h<HH; h++)
            mx[h] = fmaxf(mx[h], skT[((size_t)b*HH+h)*NN + j0 + t]);
    }
    #pragma unroll
    for(int h=0;h<HH;h++){
        #pragma unroll
        for(int off=32; off>=1; off>>=1) mx[h] = fmaxf(mx[h], __shfl_xor(mx[h], off));
    }
    __shared__ float redm[4][HH];
    __shared__ float mxL[HH];
    int w = t>>6, l = t&63;
    if(l==0){
        #pragma unroll
        for(int h=0;h<HH;h++) redm[w][h]=mx[h];
    }
    __syncthreads();
    if(t < HH) mxL[t] = fmaxf(fmaxf(redm[0][t],redm[1][t]), fmaxf(redm[2][t],redm[3][t]));
    __syncthreads();

    float Mh[HH];
    #pragma unroll
    for(int h=0; h<HH; h++){ Mh[h] = leaky(sqh[h] + mxL[h]); sum[h]=0.f; }

    const int* arow = adj + (size_t)R*NN;
    for(int j0=0; j0<NN; j0+=256){
        int a = arow[j0+t];
        if(a != 0){
            #pragma unroll
            for(int h=0; h<HH; h++){
                float s = leaky(sqh[h] + skT[((size_t)b*HH+h)*NN + j0 + t]);
                sum[h] += __expf(s - Mh[h]);
            }
        }
    }
    #pragma unroll
    for(int h=0;h<HH;h++){
        #pragma unroll
        for(int off=32; off>=1; off>>=1) sum[h] += __shfl_xor(sum[h], off);
    }
    __shared__ float red[4][HH];
    if(l==0){
        #pragma unroll
        for(int h=0;h<HH;h++) red[w][h]=sum[h];
    }
    __syncthreads();
    if(t < HH){
        float s = red[0][t]+red[1][t]+red[2][t]+red[3][t];
        Madj[(size_t)R*HH + t] = leaky(sq[(size_t)R*HH + t] + mxL[t]) + __logf(s);
    }
}

// K3: hot kernel. Per (i-tile 32, b, jc of 8): per 32-j tile:
// Phase A computes w = exp(leaky(sq+sk)-Madj) (f32 meanw, bf16 wLDS),
// staging vLDS from pre-transposed bf16 vT, Phase B MFMA. 2 barriers/tile.
#define TI 32
#define JT 32
#define JC 8
#define JPC (NN/JC)   // 256

__global__ __launch_bounds__(256, 4)
void k_attn(const int* __restrict__ adj, const float* __restrict__ sq,
            const float* __restrict__ skT, const float* __restrict__ Madj,
            const ushort* __restrict__ vT, float* __restrict__ meanw,
            ushort* __restrict__ attp){
    __shared__ __align__(16) char smem[40960];
    ushort (*wLDS)[TI][40] = (ushort (*)[TI][40])smem;           // [h][i][j] 20480B
    ushort (*vLDS)[40]     = (ushort (*)[40])(smem + 20480);     // [d][j]    20480B

    int t  = threadIdx.x;
    int it = blockIdx.x;       // 0..63
    int b  = blockIdx.y;       // 0..1
    int jc = blockIdx.z;       // 0..7
    int i0 = it*TI;
    int R0 = b*NN + i0;

    int ia = t >> 4;           // 0..15  (Phase A i within half)
    int jp = t & 15;
    int jj = jp*2;

    // per-row params in registers (rows ia and 16+ia)
    float sq1[8], sq2[8], M1[8], M2[8];
    {
        float4 a0 = *reinterpret_cast<const float4*>(&sq[(size_t)(R0+ia)*HH]);
        float4 a1 = *reinterpret_cast<const float4*>(&sq[(size_t)(R0+ia)*HH+4]);
        float4 b0 = *reinterpret_cast<const float4*>(&sq[(size_t)(R0+16+ia)*HH]);
        float4 b1 = *reinterpret_cast<const float4*>(&sq[(size_t)(R0+16+ia)*HH+4]);
        sq1[0]=a0.x; sq1[1]=a0.y; sq1[2]=a0.z; sq1[3]=a0.w;
        sq1[4]=a1.x; sq1[5]=a1.y; sq1[6]=a1.z; sq1[7]=a1.w;
        sq2[0]=b0.x; sq2[1]=b0.y; sq2[2]=b0.z; sq2[3]=b0.w;
        sq2[4]=b1.x; sq2[5]=b1.y; sq2[6]=b1.z; sq2[7]=b1.w;
        float4 c0 = *reinterpret_cast<const float4*>(&Madj[(size_t)(R0+ia)*HH]);
        float4 c1 = *reinterpret_cast<const float4*>(&Madj[(size_t)(R0+ia)*HH+4]);
        float4 d0 = *reinterpret_cast<const float4*>(&Madj[(size_t)(R0+16+ia)*HH]);
        float4 d1 = *reinterpret_cast<const float4*>(&Madj[(size_t)(R0+16+ia)*HH+4]);
        M1[0]=c0.x; M1[1]=c0.y; M1[2]=c0.z; M1[3]=c0.w;
        M1[4]=c1.x; M1[5]=c1.y; M1[6]=c1.z; M1[7]=c1.w;
        M2[0]=d0.x; M2[1]=d0.y; M2[2]=d0.z; M2[3]=d0.w;
        M2[4]=d1.x; M2[5]=d1.y; M2[6]=d1.z; M2[7]=d1.w;
    }

    int wid = t >> 6;          // wave 0..3 -> heads 2w, 2w+1
    int l   = t & 63;
    int lr  = l & 15;
    int kg  = l >> 4;          // 0..3

    f32x4 acc[2][2][2];        // [head-in-wave][mi][ni]
    #pragma unroll
    for(int hh=0;hh<2;hh++)
        #pragma unroll
        for(int mi=0;mi<2;mi++)
            #pragma unroll
            for(int ni=0;ni<2;ni++) acc[hh][mi][ni] = (f32x4){0.f,0.f,0.f,0.f};

    const ushort* vsrc = vT + ((size_t)b*DD + t)*NN;

    for(int jt0=0; jt0<JPC; jt0+=JT){
        int jb = jc*JPC + jt0;
        __syncthreads();   // previous tile's MFMA reads done

        // stage vLDS[d=t][0..32] from vT (64B per thread)
        {
            const ushort* src = vsrc + jb;
            u16x8 a0 = *reinterpret_cast<const u16x8*>(src);
            u16x8 a1 = *reinterpret_cast<const u16x8*>(src+8);
            u16x8 a2 = *reinterpret_cast<const u16x8*>(src+16);
            u16x8 a3 = *reinterpret_cast<const u16x8*>(src+24);
            *reinterpret_cast<u16x8*>(&vLDS[t][0])  = a0;
            *reinterpret_cast<u16x8*>(&vLDS[t][8])  = a1;
            *reinterpret_cast<u16x8*>(&vLDS[t][16]) = a2;
            *reinterpret_cast<u16x8*>(&vLDS[t][24]) = a3;
        }

        // Phase A: rows ia and 16+ia, cols jj, jj+1
        {
            int2 aA = *reinterpret_cast<const int2*>(&adj[((size_t)(R0+ia))*NN + jb + jj]);
            int2 aB = *reinterpret_cast<const int2*>(&adj[((size_t)(R0+16+ia))*NN + jb + jj]);
            float ws00=0.f, ws01=0.f, ws10=0.f, ws11=0.f;
            #pragma unroll
            for(int h=0; h<HH; h++){
                float2 sk2 = *reinterpret_cast<const float2*>(&skT[((size_t)b*HH+h)*NN + jb + jj]);
                float w00=0.f, w01=0.f, w10=0.f, w11=0.f;
                if(aA.x) w00 = __expf(leaky(sq1[h]+sk2.x) - M1[h]);
                if(aA.y) w01 = __expf(leaky(sq1[h]+sk2.y) - M1[h]);
                if(aB.x) w10 = __expf(leaky(sq2[h]+sk2.x) - M2[h]);
                if(aB.y) w11 = __expf(leaky(sq2[h]+sk2.y) - M2[h]);
                ws00+=w00; ws01+=w01; ws10+=w10; ws11+=w11;
                ushort2 uA; uA.x=f2bf(w00); uA.y=f2bf(w01);
                ushort2 uB; uB.x=f2bf(w10); uB.y=f2bf(w11);
                *reinterpret_cast<ushort2*>(&wLDS[h][ia][jj])    = uA;
                *reinterpret_cast<ushort2*>(&wLDS[h][16+ia][jj]) = uB;
            }
            float2 mA; mA.x = ws00*0.125f; mA.y = ws01*0.125f;
            float2 mB; mB.x = ws10*0.125f; mB.y = ws11*0.125f;
            *reinterpret_cast<float2*>(&meanw[((size_t)(R0+ia))*NN + jb + jj])    = mA;
            *reinterpret_cast<float2*>(&meanw[((size_t)(R0+16+ia))*NN + jb + jj]) = mB;
        }
        __syncthreads();

        // Phase B: MFMA. wave wid -> heads 2*wid, 2*wid+1.
        #pragma unroll
        for(int hh=0; hh<2; hh++){
            int h = wid*2 + hh;
            bf16x8 a0 = *reinterpret_cast<const bf16x8*>(&wLDS[h][lr][kg*8]);
            bf16x8 a1 = *reinterpret_cast<const bf16x8*>(&wLDS[h][16+lr][kg*8]);
            bf16x8 b0 = *reinterpret_cast<const bf16x8*>(&vLDS[h*HD + lr][kg*8]);
            bf16x8 b1 = *reinterpret_cast<const bf16x8*>(&vLDS[h*HD + 16 + lr][kg*8]);
            acc[hh][0][0] = __builtin_amdgcn_mfma_f32_16x16x32_bf16(a0, b0, acc[hh][0][0], 0,0,0);
            acc[hh][0][1] = __builtin_amdgcn_mfma_f32_16x16x32_bf16(a0, b1, acc[hh][0][1], 0,0,0);
            acc[hh][1][0] = __builtin_amdgcn_mfma_f32_16x16x32_bf16(a1, b0, acc[hh][1][0], 0,0,0);
            acc[hh][1][1] = __builtin_amdgcn_mfma_f32_16x16x32_bf16(a1, b1, acc[hh][1][1], 0,0,0);
        }
    }

    // Epilogue via LDS transpose -> coalesced bf16 stores.
    __syncthreads();
    float* fb = (float*)smem;   // 32KB: fb[i*DD + d], i=0..31
    #pragma unroll
    for(int hh=0;hh<2;hh++)
        #pragma unroll
        for(int mi=0;mi<2;mi++)
            #pragma unroll
            for(int ni=0;ni<2;ni++)
                #pragma unroll
                for(int rg=0; rg<4; rg++){
                    int i = mi*16 + kg*4 + rg;
                    int d = (wid*2+hh)*HD + ni*16 + lr;
                    fb[i*DD + d] = acc[hh][mi][ni][rg];
                }
    __syncthreads();
    {
        int i  = t >> 3;
        int d0 = (t & 7) * 32;
        size_t orow = ((size_t)(jc*BB + b)*NN + i0 + i)*DD + d0;
        #pragma unroll
        for(int c=0; c<4; c++){
            u16x8 pack;
            #pragma unroll
            for(int e=0; e<8; e++) pack[e] = f2bf(fb[i*DD + d0 + c*8 + e]);
            *reinterpret_cast<u16x8*>(&attp[orow + c*8]) = pack;
        }
    }
}

// K4: out = LN(sum(attp partials) @ Wo + bo + x)
__global__ __launch_bounds__(256, 2)
void k_out(const ushort* __restrict__ attp, const float* __restrict__ x,
           const float* __restrict__ Wo, const float* __restrict__ bo,
           const float* __restrict__ g, const float* __restrict__ bln,
           float* __restrict__ out){
    __shared__ float aL[16][DD];
    __shared__ float ps[16][16][2];
    __shared__ float muL[16], rsL[16];
    int t = threadIdx.x;
    int r0 = blockIdx.x*16;
    int b  = r0 >> 11;
    int j0 = r0 & (NN-1);
    #pragma unroll
    for(int r=0;r<16;r++){
        float s = 0.f;
        #pragma unroll
        for(int jc=0; jc<JC; jc++)
            s += bf2f(attp[((size_t)(jc*BB + b)*NN + j0 + r)*DD + t]);
        aL[r][t] = s;
    }
    __syncthreads();
    float acc[16];
    #pragma unroll
    for(int r=0;r<16;r++) acc[r]=0.f;
    for(int k=0;k<DD;k+=4){
        float w0 = Wo[(size_t)k*DD + t];
        float w1 = Wo[(size_t)(k+1)*DD + t];
        float w2 = Wo[(size_t)(k+2)*DD + t];
        float w3 = Wo[(size_t)(k+3)*DD + t];
        #pragma unroll
        for(int r=0;r<16;r++){
            float4 av = *reinterpret_cast<const float4*>(&aL[r][k]);
            acc[r] += av.x*w0 + av.y*w1 + av.z*w2 + av.w*w3;
        }
    }
    float bb = bo[t];
    #pragma unroll
    for(int r=0;r<16;r++) acc[r] += bb + x[((size_t)r0+r)*DD + t];
    __syncthreads();
    #pragma unroll
    for(int r=0;r<16;r++) aL[r][t] = acc[r];
    __syncthreads();
    {
        int rr = t>>4, seg = t&15;
        float s=0.f, sq=0.f;
        #pragma unroll
        for(int e=0;e<16;e++){
            float y = aL[rr][seg*16+e];
            s += y; sq += y*y;
        }
        ps[rr][seg][0]=s; ps[rr][seg][1]=sq;
    }
    __syncthreads();
    if(t<16){
        float s=0.f, sq=0.f;
        #pragma unroll
        for(int e=0;e<16;e++){ s+=ps[t][e][0]; sq+=ps[t][e][1]; }
        float mu = s/256.f;
        float var = sq/256.f - mu*mu;
        muL[t]=mu; rsL[t]=rsqrtf(var+EPS);
    }
    __syncthreads();
    float gg = g[t], bl = bln[t];
    #pragma unroll
    for(int r=0;r<16;r++){
        out[((size_t)r0+r)*DD + t] = (acc[r]-muL[r])*rsL[r]*gg + bl;
    }
}

extern "C" void kernel_launch(void* const* d_in, const int* in_sizes, int n_in,
                              void* d_out, int out_size, void* d_ws, size_t ws_size,
                              hipStream_t stream) {
    const float* x    = (const float*)d_in[0];
    const int*   adj  = (const int*)d_in[1];
    const float* Wq   = (const float*)d_in[2];
    const float* bq   = (const float*)d_in[3];
    const float* Wk   = (const float*)d_in[4];
    const float* bk   = (const float*)d_in[5];
    const float* Wv   = (const float*)d_in[6];
    const float* bv   = (const float*)d_in[7];
    const float* aa   = (const float*)d_in[8];
    const float* Wo   = (const float*)d_in[9];
    const float* bo   = (const float*)d_in[10];
    const float* lng  = (const float*)d_in[11];
    const float* lnb  = (const float*)d_in[12];

    float* out0  = (float*)d_out;                  // (B,N,D)
    float* meanw = out0 + (size_t)BB*NN*DD;        // (B,N,N)

    char* wsb = (char*)d_ws;
    float* uq   = (float*)wsb;                                    // 2048 f32
    float* uk   = uq + 2048;                                      // 2048
    float* cq   = uk + 2048;                                      // 16
    float* ck   = cq + 16;                                        // 16
    float* sqv  = ck + 16;                                        // 32768
    float* skT  = sqv + 32768;                                    // 32768
    float* Madj = skT + 32768;                                    // 32768
    ushort* vT  = (ushort*)(Madj + 32768);                        // B*D*N = 1048576 u16
    ushort* attp= vT + (size_t)BB*DD*NN;                          // 8*B*N*D = 8388608 u16

    k_prep<<<HH, 256, 0, stream>>>(Wq, bq, Wk, bk, aa, uq, uk, cq, ck);
    k_sqskv<<<(BB*NN)/8, 256, 0, stream>>>(x, Wv, bv, uq, uk, cq, ck, vT, sqv, skT);
    k_denom<<<BB*NN, 256, 0, stream>>>(adj, sqv, skT, Madj);
    k_attn<<<dim3(NN/TI, BB, JC), 256, 0, stream>>>(adj, sqv, skT, Madj, vT, meanw, attp);
    k_out<<<(BB*NN)/16, 256, 0, stream>>>(attp, x, Wo, bo, lng, lnb, out0);
}

// Round 6
// 135.846 us; speedup vs baseline: 1.9652x; 1.0636x over previous
//
#include <hip/hip_runtime.h>

#define BB 2
#define NN 2048
#define DD 256
#define HH 8
#define HD 32
#define EPS 1e-5f
#define L2E 1.4426950408889634f

typedef __attribute__((ext_vector_type(8))) short bf16x8;
typedef __attribute__((ext_vector_type(4))) float f32x4;
typedef __attribute__((ext_vector_type(8))) unsigned short u16x8;

// leaky in log2-scaled domain: leaky(c*z) = c*leaky(z), c>0. leaky(z)=max(z,0.2z).
__device__ __forceinline__ float lky(float z){ return fmaxf(z, 0.2f*z); }

__device__ __forceinline__ ushort f2bf(float f){
    union{ float f; unsigned u; } c; c.f = f;
    unsigned r = c.u + 0x7fffu + ((c.u >> 16) & 1u);
    return (ushort)(r >> 16);
}
__device__ __forceinline__ float bf2f(ushort u){
    union{ unsigned u; float f; } c; c.u = ((unsigned)u) << 16; return c.f;
}
__device__ __forceinline__ unsigned cvtpk(float lo, float hi){
    unsigned r;
    asm("v_cvt_pk_bf16_f32 %0, %1, %2" : "=v"(r) : "v"(lo), "v"(hi));
    return r;
}

// K0: uq[h][d], uk[h][d], cq[h], ck[h] — all pre-scaled by log2(e)
__global__ void k_prep(const float* __restrict__ Wq, const float* __restrict__ bq,
                       const float* __restrict__ Wk, const float* __restrict__ bk,
                       const float* __restrict__ aa, float* __restrict__ uq,
                       float* __restrict__ uk, float* __restrict__ cq, float* __restrict__ ck){
    int h = blockIdx.x;      // 0..7
    int d = threadIdx.x;     // 0..255
    float accq = 0.f, acck = 0.f;
    #pragma unroll
    for(int t=0; t<HD; t++){
        accq += Wq[(size_t)d*DD + h*HD + t] * aa[h*2*HD + t];
        acck += Wk[(size_t)d*DD + h*HD + t] * aa[h*2*HD + HD + t];
    }
    uq[h*DD + d] = accq * L2E;
    uk[h*DD + d] = acck * L2E;
    __shared__ float red[64];
    if(d < HD){
        red[d]      = bq[h*HD+d]*aa[h*2*HD+d];
        red[32+d]   = bk[h*HD+d]*aa[h*2*HD+HD+d];
    }
    __syncthreads();
    if(d==0){ float s=0.f; for(int t=0;t<32;t++) s+=red[t];    cq[h]=s*L2E; }
    if(d==1){ float s=0.f; for(int t=0;t<32;t++) s+=red[32+t]; ck[h]=s*L2E; }
}

// K1 fused: per block of 4 rows: v^T bf16 projection + sq/skH scores (log2-domain).
__global__ __launch_bounds__(256, 2)
void k_sqskv(const float* __restrict__ x, const float* __restrict__ Wv,
             const float* __restrict__ bv, const float* __restrict__ uq,
             const float* __restrict__ uk, const float* __restrict__ cq,
             const float* __restrict__ ck, ushort* __restrict__ vT,
             float* __restrict__ sq, float* __restrict__ skH){
    __shared__ float uqL[HH*DD];    // 8KB
    __shared__ float ukL[HH*DD];    // 8KB
    __shared__ float xL[4][DD];     // 4KB
    int t = threadIdx.x;
    int r0 = blockIdx.x * 4;        // global row
    int b  = r0 >> 11;
    int j0 = r0 & (NN-1);
    #pragma unroll
    for(int i=0;i<8;i++){
        uqL[i*DD + t] = uq[i*DD + t];
        ukL[i*DD + t] = uk[i*DD + t];
    }
    #pragma unroll
    for(int i=0;i<4;i++) xL[i][t] = x[((size_t)r0+i)*DD + t];
    __syncthreads();

    // vproj: thread = col t, 4 rows
    float acc[4];
    #pragma unroll
    for(int r=0;r<4;r++) acc[r]=0.f;
    for(int k=0;k<DD;k+=4){
        float w0 = Wv[(size_t)k*DD + t];
        float w1 = Wv[(size_t)(k+1)*DD + t];
        float w2 = Wv[(size_t)(k+2)*DD + t];
        float w3 = Wv[(size_t)(k+3)*DD + t];
        #pragma unroll
        for(int r=0;r<4;r++){
            float4 xv = *reinterpret_cast<const float4*>(&xL[r][k]);
            acc[r] += xv.x*w0 + xv.y*w1 + xv.z*w2 + xv.w*w3;
        }
    }
    {
        float bb = bv[t];
        ushort4 pack;
        pack.x = f2bf(acc[0] + bb);
        pack.y = f2bf(acc[1] + bb);
        pack.z = f2bf(acc[2] + bb);
        pack.w = f2bf(acc[3] + bb);
        *reinterpret_cast<ushort4*>(&vT[((size_t)b*DD + t)*NN + j0]) = pack;  // vT[b][d][j]
    }

    // sqsk: wave wid -> row wid
    int wid = t >> 6, l = t & 63;
    int R = r0 + wid;
    float4 xv = *reinterpret_cast<const float4*>(&xL[wid][l*4]);
    float vq = 0.f, vk = 0.f;
    #pragma unroll
    for(int h=0; h<HH; h++){
        float4 uqv = *reinterpret_cast<const float4*>(&uqL[h*DD + l*4]);
        float4 ukv = *reinterpret_cast<const float4*>(&ukL[h*DD + l*4]);
        float aq = xv.x*uqv.x + xv.y*uqv.y + xv.z*uqv.z + xv.w*uqv.w;
        float ak = xv.x*ukv.x + xv.y*ukv.y + xv.z*ukv.z + xv.w*ukv.w;
        #pragma unroll
        for(int off=32; off>=1; off>>=1){
            aq += __shfl_xor(aq, off);
            ak += __shfl_xor(ak, off);
        }
        if(l == h){ vq = aq; vk = ak; }
    }
    if(l < HH){
        sq[(size_t)R*HH + l] = vq + cq[l];
        skH[((size_t)b*NN + (R & (NN-1)))*HH + l] = vk + ck[l];
    }
}

// K1b: Mk[b][h] = max_j skH[b][j][h]
__global__ void k_maxsk(const float* __restrict__ skH, float* __restrict__ Mk){
    int b = blockIdx.x >> 3, h = blockIdx.x & 7;
    int t = threadIdx.x;   // 256
    float m = -1e30f;
    for(int j=t; j<NN; j+=256) m = fmaxf(m, skH[((size_t)b*NN + j)*HH + h]);
    #pragma unroll
    for(int off=32; off>=1; off>>=1) m = fmaxf(m, __shfl_xor(m, off));
    __shared__ float red[4];
    if((t&63)==0) red[t>>6] = m;
    __syncthreads();
    if(t==0) Mk[blockIdx.x] = fmaxf(fmaxf(red[0],red[1]), fmaxf(red[2],red[3]));
}

// K2: single pass: Madj[R][h] = Mh + log2(sum_allowed exp2(s' - Mh)), Mh = lky(sq'+Mk')
__global__ void k_denom(const int* __restrict__ adj, const float* __restrict__ sq,
                        const float* __restrict__ skH, const float* __restrict__ Mk,
                        float* __restrict__ Madj){
    int R = blockIdx.x;           // b*N + i
    int b = R >> 11;
    int t = threadIdx.x;
    float sqh[HH], Mh[HH], sum[HH];
    {
        float4 a0 = *reinterpret_cast<const float4*>(&sq[(size_t)R*HH]);
        float4 a1 = *reinterpret_cast<const float4*>(&sq[(size_t)R*HH+4]);
        float4 m0 = *reinterpret_cast<const float4*>(&Mk[b*HH]);
        float4 m1 = *reinterpret_cast<const float4*>(&Mk[b*HH+4]);
        sqh[0]=a0.x; sqh[1]=a0.y; sqh[2]=a0.z; sqh[3]=a0.w;
        sqh[4]=a1.x; sqh[5]=a1.y; sqh[6]=a1.z; sqh[7]=a1.w;
        Mh[0]=lky(sqh[0]+m0.x); Mh[1]=lky(sqh[1]+m0.y);
        Mh[2]=lky(sqh[2]+m0.z); Mh[3]=lky(sqh[3]+m0.w);
        Mh[4]=lky(sqh[4]+m1.x); Mh[5]=lky(sqh[5]+m1.y);
        Mh[6]=lky(sqh[6]+m1.z); Mh[7]=lky(sqh[7]+m1.w);
    }
    #pragma unroll
    for(int h=0;h<HH;h++) sum[h]=0.f;

    const int* arow = adj + (size_t)R*NN;
    for(int j0=0; j0<NN; j0+=256){
        int j = j0 + t;
        int a = arow[j];
        float4 s0 = *reinterpret_cast<const float4*>(&skH[((size_t)b*NN + j)*HH]);
        float4 s1 = *reinterpret_cast<const float4*>(&skH[((size_t)b*NN + j)*HH+4]);
        float sk[8] = {s0.x,s0.y,s0.z,s0.w,s1.x,s1.y,s1.z,s1.w};
        #pragma unroll
        for(int h=0; h<HH; h++){
            float e = exp2f(lky(sqh[h]+sk[h]) - Mh[h]);
            if(a) sum[h] += e;
        }
    }
    #pragma unroll
    for(int h=0;h<HH;h++){
        #pragma unroll
        for(int off=32; off>=1; off>>=1) sum[h] += __shfl_xor(sum[h], off);
    }
    __shared__ float red[4][HH];
    int w = t>>6, l = t&63;
    if(l==0){
        #pragma unroll
        for(int h=0;h<HH;h++) red[w][h]=sum[h];
    }
    __syncthreads();
    if(t < HH){
        float s = red[0][t]+red[1][t]+red[2][t]+red[3][t];
        Madj[(size_t)R*HH + t] = Mh[t] + log2f(s);
    }
}

// K3: hot kernel. log2-domain scores, cvt_pk bf16 packing, skH 8-head loads.
#define TI 32
#define JT 32
#define JC 8
#define JPC (NN/JC)   // 256

__global__ __launch_bounds__(256, 4)
void k_attn(const int* __restrict__ adj, const float* __restrict__ sq,
            const float* __restrict__ skH, const float* __restrict__ Madj,
            const ushort* __restrict__ vT, float* __restrict__ meanw,
            ushort* __restrict__ attp){
    __shared__ __align__(16) char smem[40960];
    ushort (*wLDS)[TI][40] = (ushort (*)[TI][40])smem;           // [h][i][j] 20480B
    ushort (*vLDS)[40]     = (ushort (*)[40])(smem + 20480);     // [d][j]    20480B

    int t  = threadIdx.x;
    int it = blockIdx.x;       // 0..63
    int b  = blockIdx.y;       // 0..1
    int jc = blockIdx.z;       // 0..7
    int i0 = it*TI;
    int R0 = b*NN + i0;

    int ia = t >> 4;           // 0..15  (Phase A i within half)
    int jp = t & 15;
    int jj = jp*2;

    // per-row params in registers (rows ia and 16+ia), already log2-scaled
    float sq1[8], sq2[8], M1[8], M2[8];
    {
        float4 a0 = *reinterpret_cast<const float4*>(&sq[(size_t)(R0+ia)*HH]);
        float4 a1 = *reinterpret_cast<const float4*>(&sq[(size_t)(R0+ia)*HH+4]);
        float4 b0 = *reinterpret_cast<const float4*>(&sq[(size_t)(R0+16+ia)*HH]);
        float4 b1 = *reinterpret_cast<const float4*>(&sq[(size_t)(R0+16+ia)*HH+4]);
        sq1[0]=a0.x; sq1[1]=a0.y; sq1[2]=a0.z; sq1[3]=a0.w;
        sq1[4]=a1.x; sq1[5]=a1.y; sq1[6]=a1.z; sq1[7]=a1.w;
        sq2[0]=b0.x; sq2[1]=b0.y; sq2[2]=b0.z; sq2[3]=b0.w;
        sq2[4]=b1.x; sq2[5]=b1.y; sq2[6]=b1.z; sq2[7]=b1.w;
        float4 c0 = *reinterpret_cast<const float4*>(&Madj[(size_t)(R0+ia)*HH]);
        float4 c1 = *reinterpret_cast<const float4*>(&Madj[(size_t)(R0+ia)*HH+4]);
        float4 d0 = *reinterpret_cast<const float4*>(&Madj[(size_t)(R0+16+ia)*HH]);
        float4 d1 = *reinterpret_cast<const float4*>(&Madj[(size_t)(R0+16+ia)*HH+4]);
        M1[0]=c0.x; M1[1]=c0.y; M1[2]=c0.z; M1[3]=c0.w;
        M1[4]=c1.x; M1[5]=c1.y; M1[6]=c1.z; M1[7]=c1.w;
        M2[0]=d0.x; M2[1]=d0.y; M2[2]=d0.z; M2[3]=d0.w;
        M2[4]=d1.x; M2[5]=d1.y; M2[6]=d1.z; M2[7]=d1.w;
    }

    int wid = t >> 6;          // wave 0..3 -> heads 2w, 2w+1
    int l   = t & 63;
    int lr  = l & 15;
    int kg  = l >> 4;          // 0..3

    f32x4 acc[2][2][2];
    #pragma unroll
    for(int hh=0;hh<2;hh++)
        #pragma unroll
        for(int mi=0;mi<2;mi++)
            #pragma unroll
            for(int ni=0;ni<2;ni++) acc[hh][mi][ni] = (f32x4){0.f,0.f,0.f,0.f};

    const ushort* vsrc = vT + ((size_t)b*DD + t)*NN;
    const int* adjA = adj + (size_t)(R0+ia)*NN;
    const int* adjB = adj + (size_t)(R0+16+ia)*NN;
    const float* skbase = skH + (size_t)b*NN*HH;

    for(int jt0=0; jt0<JPC; jt0+=JT){
        int jb = jc*JPC + jt0;
        __syncthreads();   // previous tile's MFMA reads done

        // stage vLDS[d=t][0..32] from vT (64B per thread)
        {
            const ushort* src = vsrc + jb;
            u16x8 a0 = *reinterpret_cast<const u16x8*>(src);
            u16x8 a1 = *reinterpret_cast<const u16x8*>(src+8);
            u16x8 a2 = *reinterpret_cast<const u16x8*>(src+16);
            u16x8 a3 = *reinterpret_cast<const u16x8*>(src+24);
            *reinterpret_cast<u16x8*>(&vLDS[t][0])  = a0;
            *reinterpret_cast<u16x8*>(&vLDS[t][8])  = a1;
            *reinterpret_cast<u16x8*>(&vLDS[t][16]) = a2;
            *reinterpret_cast<u16x8*>(&vLDS[t][24]) = a3;
        }

        // Phase A: rows ia and 16+ia, cols jj, jj+1
        {
            float4 p0 = *reinterpret_cast<const float4*>(&skbase[(size_t)(jb+jj)*HH]);
            float4 p1 = *reinterpret_cast<const float4*>(&skbase[(size_t)(jb+jj)*HH+4]);
            float4 q0 = *reinterpret_cast<const float4*>(&skbase[(size_t)(jb+jj+1)*HH]);
            float4 q1 = *reinterpret_cast<const float4*>(&skbase[(size_t)(jb+jj+1)*HH+4]);
            float ska[8] = {p0.x,p0.y,p0.z,p0.w,p1.x,p1.y,p1.z,p1.w};
            float skb[8] = {q0.x,q0.y,q0.z,q0.w,q1.x,q1.y,q1.z,q1.w};
            int2 aA = *reinterpret_cast<const int2*>(&adjA[jb + jj]);
            int2 aB = *reinterpret_cast<const int2*>(&adjB[jb + jj]);
            float ws00=0.f, ws01=0.f, ws10=0.f, ws11=0.f;
            #pragma unroll
            for(int h=0; h<HH; h++){
                float e00 = exp2f(lky(sq1[h]+ska[h]) - M1[h]);
                float e01 = exp2f(lky(sq1[h]+skb[h]) - M1[h]);
                float e10 = exp2f(lky(sq2[h]+ska[h]) - M2[h]);
                float e11 = exp2f(lky(sq2[h]+skb[h]) - M2[h]);
                float w00 = aA.x ? e00 : 0.f;
                float w01 = aA.y ? e01 : 0.f;
                float w10 = aB.x ? e10 : 0.f;
                float w11 = aB.y ? e11 : 0.f;
                ws00+=w00; ws01+=w01; ws10+=w10; ws11+=w11;
                *reinterpret_cast<unsigned*>(&wLDS[h][ia][jj])    = cvtpk(w00, w01);
                *reinterpret_cast<unsigned*>(&wLDS[h][16+ia][jj]) = cvtpk(w10, w11);
            }
            float2 mA; mA.x = ws00*0.125f; mA.y = ws01*0.125f;
            float2 mB; mB.x = ws10*0.125f; mB.y = ws11*0.125f;
            *reinterpret_cast<float2*>(&meanw[((size_t)(R0+ia))*NN + jb + jj])    = mA;
            *reinterpret_cast<float2*>(&meanw[((size_t)(R0+16+ia))*NN + jb + jj]) = mB;
        }
        __syncthreads();

        // Phase B: MFMA. wave wid -> heads 2*wid, 2*wid+1.
        #pragma unroll
        for(int hh=0; hh<2; hh++){
            int h = wid*2 + hh;
            bf16x8 a0 = *reinterpret_cast<const bf16x8*>(&wLDS[h][lr][kg*8]);
            bf16x8 a1 = *reinterpret_cast<const bf16x8*>(&wLDS[h][16+lr][kg*8]);
            bf16x8 b0 = *reinterpret_cast<const bf16x8*>(&vLDS[h*HD + lr][kg*8]);
            bf16x8 b1 = *reinterpret_cast<const bf16x8*>(&vLDS[h*HD + 16 + lr][kg*8]);
            acc[hh][0][0] = __builtin_amdgcn_mfma_f32_16x16x32_bf16(a0, b0, acc[hh][0][0], 0,0,0);
            acc[hh][0][1] = __builtin_amdgcn_mfma_f32_16x16x32_bf16(a0, b1, acc[hh][0][1], 0,0,0);
            acc[hh][1][0] = __builtin_amdgcn_mfma_f32_16x16x32_bf16(a1, b0, acc[hh][1][0], 0,0,0);
            acc[hh][1][1] = __builtin_amdgcn_mfma_f32_16x16x32_bf16(a1, b1, acc[hh][1][1], 0,0,0);
        }
    }

    // Epilogue via LDS transpose -> coalesced bf16 stores.
    __syncthreads();
    float* fb = (float*)smem;   // 32KB: fb[i*DD + d]
    #pragma unroll
    for(int hh=0;hh<2;hh++)
        #pragma unroll
        for(int mi=0;mi<2;mi++)
            #pragma unroll
            for(int ni=0;ni<2;ni++)
                #pragma unroll
                for(int rg=0; rg<4; rg++){
                    int i = mi*16 + kg*4 + rg;
                    int d = (wid*2+hh)*HD + ni*16 + lr;
                    fb[i*DD + d] = acc[hh][mi][ni][rg];
                }
    __syncthreads();
    {
        int i  = t >> 3;
        int d0 = (t & 7) * 32;
        size_t orow = ((size_t)(jc*BB + b)*NN + i0 + i)*DD + d0;
        #pragma unroll
        for(int c=0; c<4; c++){
            unsigned p0 = cvtpk(fb[i*DD + d0 + c*8 + 0], fb[i*DD + d0 + c*8 + 1]);
            unsigned p1 = cvtpk(fb[i*DD + d0 + c*8 + 2], fb[i*DD + d0 + c*8 + 3]);
            unsigned p2 = cvtpk(fb[i*DD + d0 + c*8 + 4], fb[i*DD + d0 + c*8 + 5]);
            unsigned p3 = cvtpk(fb[i*DD + d0 + c*8 + 6], fb[i*DD + d0 + c*8 + 7]);
            uint4 pk; pk.x=p0; pk.y=p1; pk.z=p2; pk.w=p3;
            *reinterpret_cast<uint4*>(&attp[orow + c*8]) = pk;
        }
    }
}

// K4: out = LN(sum(attp partials) @ Wo + bo + x), 8 rows/block
__global__ __launch_bounds__(256, 2)
void k_out(const ushort* __restrict__ attp, const float* __restrict__ x,
           const float* __restrict__ Wo, const float* __restrict__ bo,
           const float* __restrict__ g, const float* __restrict__ bln,
           float* __restrict__ out){
    __shared__ float aL[8][DD];
    __shared__ float ps[8][32][2];
    __shared__ float muL[8], rsL[8];
    int t = threadIdx.x;
    int r0 = blockIdx.x*8;
    int b  = r0 >> 11;
    int j0 = r0 & (NN-1);

    // sum partials, vectorized: thread t -> row t>>5, d-octet (t&31)*8
    {
        int rr = t >> 5;
        int d0 = (t & 31) * 8;
        float s8[8];
        #pragma unroll
        for(int e=0;e<8;e++) s8[e]=0.f;
        #pragma unroll
        for(int jc=0; jc<JC; jc++){
            u16x8 v = *reinterpret_cast<const u16x8*>(&attp[((size_t)(jc*BB + b)*NN + j0 + rr)*DD + d0]);
            #pragma unroll
            for(int e=0;e<8;e++) s8[e] += bf2f(v[e]);
        }
        #pragma unroll
        for(int e=0;e<8;e++) aL[rr][d0+e] = s8[e];
    }
    __syncthreads();

    float acc[8];
    #pragma unroll
    for(int r=0;r<8;r++) acc[r]=0.f;
    for(int k=0;k<DD;k+=4){
        float w0 = Wo[(size_t)k*DD + t];
        float w1 = Wo[(size_t)(k+1)*DD + t];
        float w2 = Wo[(size_t)(k+2)*DD + t];
        float w3 = Wo[(size_t)(k+3)*DD + t];
        #pragma unroll
        for(int r=0;r<8;r++){
            float4 av = *reinterpret_cast<const float4*>(&aL[r][k]);
            acc[r] += av.x*w0 + av.y*w1 + av.z*w2 + av.w*w3;
        }
    }
    float bb = bo[t];
    #pragma unroll
    for(int r=0;r<8;r++) acc[r] += bb + x[((size_t)r0+r)*DD + t];
    __syncthreads();
    #pragma unroll
    for(int r=0;r<8;r++) aL[r][t] = acc[r];
    __syncthreads();
    {
        int rr = t>>5, seg = t&31;
        float s=0.f, sqs=0.f;
        #pragma unroll
        for(int e=0;e<8;e++){
            float y = aL[rr][seg*8+e];
            s += y; sqs += y*y;
        }
        ps[rr][seg][0]=s; ps[rr][seg][1]=sqs;
    }
    __syncthreads();
    if(t<8){
        float s=0.f, sqs=0.f;
        #pragma unroll
        for(int e=0;e<32;e++){ s+=ps[t][e][0]; sqs+=ps[t][e][1]; }
        float mu = s/256.f;
        float var = sqs/256.f - mu*mu;
        muL[t]=mu; rsL[t]=rsqrtf(var+EPS);
    }
    __syncthreads();
    float gg = g[t], bl = bln[t];
    #pragma unroll
    for(int r=0;r<8;r++){
        out[((size_t)r0+r)*DD + t] = (acc[r]-muL[r])*rsL[r]*gg + bl;
    }
}

extern "C" void kernel_launch(void* const* d_in, const int* in_sizes, int n_in,
                              void* d_out, int out_size, void* d_ws, size_t ws_size,
                              hipStream_t stream) {
    const float* x    = (const float*)d_in[0];
    const int*   adj  = (const int*)d_in[1];
    const float* Wq   = (const float*)d_in[2];
    const float* bq   = (const float*)d_in[3];
    const float* Wk   = (const float*)d_in[4];
    const float* bk   = (const float*)d_in[5];
    const float* Wv   = (const float*)d_in[6];
    const float* bv   = (const float*)d_in[7];
    const float* aa   = (const float*)d_in[8];
    const float* Wo   = (const float*)d_in[9];
    const float* bo   = (const float*)d_in[10];
    const float* lng  = (const float*)d_in[11];
    const float* lnb  = (const float*)d_in[12];

    float* out0  = (float*)d_out;                  // (B,N,D)
    float* meanw = out0 + (size_t)BB*NN*DD;        // (B,N,N)

    char* wsb = (char*)d_ws;
    float* uq   = (float*)wsb;                                    // 2048 f32
    float* uk   = uq + 2048;                                      // 2048
    float* cq   = uk + 2048;                                      // 16
    float* ck   = cq + 16;                                        // 16
    float* Mk   = ck + 16;                                        // 16
    float* sqv  = Mk + 16;                                        // 32768
    float* skH  = sqv + 32768;                                    // 32768
    float* Madj = skH + 32768;                                    // 32768
    ushort* vT  = (ushort*)(Madj + 32768);                        // B*D*N u16
    ushort* attp= vT + (size_t)BB*DD*NN;                          // 8*B*N*D u16

    k_prep<<<HH, 256, 0, stream>>>(Wq, bq, Wk, bk, aa, uq, uk, cq, ck);
    k_sqskv<<<(BB*NN)/4, 256, 0, stream>>>(x, Wv, bv, uq, uk, cq, ck, vT, sqv, skH);
    k_maxsk<<<BB*HH, 256, 0, stream>>>(skH, Mk);
    k_denom<<<BB*NN, 256, 0, stream>>>(adj, sqv, skH, Mk, Madj);
    k_attn<<<dim3(NN/TI, BB, JC), 256, 0, stream>>>(adj, sqv, skH, Madj, vT, meanw, attp);
    k_out<<<(BB*NN)/8, 256, 0, stream>>>(attp, x, Wo, bo, lng, lnb, out0);
}